// Round 11
// baseline (455.797 us; speedup 1.0000x reference)
//
#include <hip/hip_runtime.h>

typedef unsigned short u16;
typedef unsigned int   u32;
typedef __attribute__((ext_vector_type(8))) short short8;
typedef __attribute__((ext_vector_type(4))) float f32x4;

typedef __attribute__((address_space(1))) const void GASV;
typedef __attribute__((address_space(3))) void LASV;

#define IMG_BYTES  557568      /* 66*66*64*2 (padded bf16 image) */
#define WS_SCALE   0
#define WS_SHIFT   256
#define WS_PART    512
#define WS_W1      8704                      /* 9 stages * 24576 B = 221184 */
#define WS_W2      229888                    /* 36 (18st x 2oh) * 12288 B = 442368 */
#define WS_BNXP    672256                    /* 64 * IMG_BYTES */
#define WS_HC      (WS_BNXP + (size_t)64*IMG_BYTES)
#define WS_CSTATE  (WS_HC + (size_t)16*IMG_BYTES)
#define WS_Y       (WS_CSTATE + 4194304ULL)  /* 64*4096*192 f32 = 201.3 MB */

#define STEP_SMEM  77664       /* 28512 input + 4*12288 ring */

__device__ __forceinline__ u16 f2b(float f){
  u32 x = __float_as_uint(f);
  return (u16)((x + 0x7fffu + ((x>>16)&1u)) >> 16);
}
__device__ __forceinline__ float sigm(float x){ return 1.f/(1.f+__expf(-x)); }
__device__ __forceinline__ float tanh_(float x){
  float e = __expf(2.f*fabsf(x));
  float t = 1.f - 2.f/(e+1.f);
  return copysignf(t, x);
}

/* ---- weight transform ----
   W1 (conv1, reg-load layout): u16 idx = stage*12288 + (cc*12+gate*4+og)*512 + lane*8 + e
   W2 (c2h,h2h, DMA layout):    u16 idx = ((st*2+oh)*12 + cc*6+gate*2+og2)*512 + lane*8 + e
   st = js*9+tap, js: 0=c2h 1=h2h */
__global__ void k_wt(const float* __restrict__ c1, const float* __restrict__ c2h,
                     const float* __restrict__ h2h, u16* __restrict__ w1,
                     u16* __restrict__ w2){
  int idx = blockIdx.x*256 + threadIdx.x;   /* 1296*256 = 331776 */
  int e = idx & 7;
  int lane = (idx >> 3) & 63;
  if (idx < 110592){
    int v = idx >> 9;
    int f3 = v % 24, stage = v / 24;
    int cc = f3 / 12, gate = (f3 % 12) >> 2, og = f3 & 3;
    int och = gate*64 + og*16 + (lane & 15);
    int c = cc*32 + (lane >> 4)*8 + e;
    w1[idx] = f2b(c1[(och*64 + c)*9 + stage]);
  } else {
    int i2 = idx - 110592;
    int v = i2 >> 9;
    int f2v = v % 12;
    int oh = (v / 12) & 1;
    int st = v / 24;
    int cc = f2v / 6, gate = (f2v % 6) >> 1, og2 = f2v & 1;
    int js = st / 9, tap = st % 9;
    int och = gate*64 + (oh*2 + og2)*16 + (lane & 15);
    int c = cc*32 + (lane >> 4)*8 + e;
    const float* src = js ? h2h : c2h;
    w2[i2] = f2b(src[(och*64 + c)*9 + tap]);
  }
}

/* ---- BN partial sums ---- */
__global__ void k_bnsum(const float* __restrict__ x, float* __restrict__ part){
  int c = blockIdx.x & 63, g = blockIdx.x >> 6;
  int tid = threadIdx.x, w = tid >> 6, lane = tid & 63;
  float s = 0.f, s2 = 0.f;
  for (int im = 0; im < 4; ++im){
    const float* base = x + (((size_t)((g*4+im)*64 + c)) << 12);
    #pragma unroll
    for (int it = 0; it < 4; ++it){
      float4 v = *(const float4*)(base + (((it<<8) + tid) << 2));
      s  += v.x + v.y + v.z + v.w;
      s2 += v.x*v.x + v.y*v.y + v.z*v.z + v.w*v.w;
    }
  }
  #pragma unroll
  for (int off = 32; off > 0; off >>= 1){
    s  += __shfl_down(s,  off);
    s2 += __shfl_down(s2, off);
  }
  __shared__ float red[8];
  if (lane == 0){ red[w] = s; red[4+w] = s2; }
  __syncthreads();
  if (tid == 0){
    part[(g<<7) + c] = red[0]+red[1]+red[2]+red[3];
    part[(g<<7) + 64 + c] = red[4]+red[5]+red[6]+red[7];
  }
}

__global__ void k_bnfin(const float* __restrict__ part, const float* __restrict__ gamma,
                        const float* __restrict__ beta, float* __restrict__ scale,
                        float* __restrict__ shift){
  int c = threadIdx.x;
  float S = 0.f, S2 = 0.f;
  for (int g = 0; g < 16; ++g){ S += part[(g<<7)+c]; S2 += part[(g<<7)+64+c]; }
  const float inv = 1.f/262144.f;
  float mean = S*inv;
  float var  = S2*inv - mean*mean;
  float sc = gamma[c] * rsqrtf(var + 1e-5f);
  scale[c] = sc;
  shift[c] = beta[c] - mean*sc;
}

/* ---- BN apply -> padded bf16 [img][66][66][64]; self-haloed ---- */
__global__ void k_bnx(const float* __restrict__ x, const float* __restrict__ scale,
                      const float* __restrict__ shift, char* __restrict__ bnxp){
  int img = blockIdx.x / 66, rp = blockIdx.x % 66;
  int tid = threadIdx.x;
  char* dstrow = bnxp + (size_t)img*IMG_BYTES + (size_t)rp*8448;
  const uint4 z = {0,0,0,0};
  if (rp == 0 || rp == 65){
    for (int i = tid; i < 528; i += 256) ((uint4*)dstrow)[i] = z;
    return;
  }
  if (tid < 16)
    *(uint4*)(dstrow + (tid>>3)*(65*128) + (tid&7)*16) = z;
  int r = rp - 1;
  int col = tid & 63, cq = tid >> 6;
  const float* xb = x + (((size_t)(img*64 + cq*16)) << 12) + (r<<6) + col;
  union { u16 u[16]; uint4 v[2]; } pk;
  #pragma unroll
  for (int i = 0; i < 16; ++i){
    int c = cq*16 + i;
    pk.u[i] = f2b(xb[((size_t)i) << 12]*scale[c] + shift[c]);
  }
  char* dst = dstrow + (size_t)(col + 1)*128 + cq*32;
  *(uint4*)dst = pk.v[0];
  *(uint4*)(dst+16) = pk.v[1];
}

/* ---- batched conv1 + bias -> y[img][p][192] f32. 2048 blocks (img, row-pair),
        512 thr = 8 waves (wr, og). Deep block queue hides all latency. ---- */
#define LOADA1(BUF, S) do {                                                     \
  const char* ap_ = w1 + (size_t)(S)*24576 + (og<<10) + (lane<<4);              \
  BUF[0] = *(const short8*)(ap_);                                               \
  BUF[1] = *(const short8*)(ap_ + 4096);                                        \
  BUF[2] = *(const short8*)(ap_ + 8192);                                        \
  BUF[3] = *(const short8*)(ap_ + 12288);                                       \
  BUF[4] = *(const short8*)(ap_ + 16384);                                       \
  BUF[5] = *(const short8*)(ap_ + 20480);                                       \
} while(0)

#define COMPUTE1(BUF, S) do {                                                   \
  const int kh_ = (S)/3, kw_ = (S)%3;                                           \
  const char* ib_ = smem + (wr + kh_)*9504 + (kw_ + l15)*144 + (l4<<4);         \
  _Pragma("unroll")                                                             \
  for (int cc = 0; cc < 2; ++cc){                                               \
    _Pragma("unroll")                                                           \
    for (int cf = 0; cf < 4; ++cf){                                             \
      short8 bf = *(const short8*)(ib_ + (cf<<4)*144 + (cc<<6));                \
      acc[0][cf] = __builtin_amdgcn_mfma_f32_16x16x32_bf16(BUF[cc*3+0], bf, acc[0][cf], 0,0,0); \
      acc[1][cf] = __builtin_amdgcn_mfma_f32_16x16x32_bf16(BUF[cc*3+1], bf, acc[1][cf], 0,0,0); \
      acc[2][cf] = __builtin_amdgcn_mfma_f32_16x16x32_bf16(BUF[cc*3+2], bf, acc[2][cf], 0,0,0); \
    }                                                                           \
  }                                                                             \
} while(0)

__global__ __launch_bounds__(512, 1) void k_conv1(
    const char* __restrict__ bnxp, const char* __restrict__ w1,
    const float* __restrict__ b1, float* __restrict__ y)
{
  __shared__ __align__(16) char smem[38016];   /* 4 rows * 66 * 144 B */
  const int tid = threadIdx.x;
  const int w = tid >> 6, lane = tid & 63;
  const int l15 = lane & 15, l4 = lane >> 4;
  const int wr = w >> 2, og = w & 3;
  const int img = blockIdx.x >> 5, rp = blockIdx.x & 31;

  const char* gb = bnxp + (size_t)img*IMG_BYTES + (size_t)rp*16896;
  for (int i = tid; i < 2112; i += 512){
    int rr = i / 528, iw = i % 528;
    *(uint4*)(smem + rr*9504 + (iw>>3)*144 + (iw&7)*16) =
        *(const uint4*)(gb + rr*8448 + iw*16);
  }

  float bv[12];
  #pragma unroll
  for (int gate = 0; gate < 3; ++gate)
    #pragma unroll
    for (int reg = 0; reg < 4; ++reg)
      bv[gate*4+reg] = b1[gate*64 + og*16 + l4*4 + reg];

  f32x4 acc[3][4];
  #pragma unroll
  for (int a = 0; a < 3; ++a)
    #pragma unroll
    for (int b = 0; b < 4; ++b)
      acc[a][b] = (f32x4){0.f,0.f,0.f,0.f};

  short8 buf0[6], buf1[6];
  LOADA1(buf0, 0);
  __syncthreads();
  #pragma unroll
  for (int s = 0; s < 4; ++s){
    LOADA1(buf1, 2*s+1);
    COMPUTE1(buf0, 2*s);
    LOADA1(buf0, 2*s+2);
    COMPUTE1(buf1, 2*s+1);
  }
  COMPUTE1(buf0, 8);

  const int r = rp*2 + wr;
  float* yb = y + ((size_t)img*4096 + (size_t)r*64)*192;
  #pragma unroll
  for (int cf = 0; cf < 4; ++cf){
    const int col = (cf<<4) + l15;
    #pragma unroll
    for (int gate = 0; gate < 3; ++gate){
      f32x4 v = acc[gate][cf];
      v[0] += bv[gate*4+0]; v[1] += bv[gate*4+1];
      v[2] += bv[gate*4+2]; v[3] += bv[gate*4+3];
      *(f32x4*)(yb + (size_t)col*192 + gate*64 + og*16 + l4*4) = v;
    }
  }
}

/* ---- fused LSTM step: c2h+h2h convs (18 stages) + gates. 512 blocks =
        (n, row, oh). 256 thr = 4 waves (og2, ch). acc init from y.
        Weight DMA ring (4-deep), fused vmcnt+barrier. 2 blocks/CU. ---- */
#define STAGE2(U) do {                                                          \
  int js_ = (U)/9, tv_ = ((U)%9 + tp); if (tv_ >= 9) tv_ -= 9;                  \
  const char* gs_ = w2 + ((size_t)((js_*9 + tv_)*2 + oh))*12288 + w*3072 + lane*16; \
  char* ls_ = smem + 28512 + ((U)&3)*12288 + w*3072;                            \
  __builtin_amdgcn_global_load_lds((GASV*)(gs_),        (LASV*)(ls_),        16, 0, 0); \
  __builtin_amdgcn_global_load_lds((GASV*)(gs_ + 1024), (LASV*)(ls_ + 1024), 16, 0, 0); \
  __builtin_amdgcn_global_load_lds((GASV*)(gs_ + 2048), (LASV*)(ls_ + 2048), 16, 0, 0); \
} while(0)

#define WAITN_BAR(N) do {                                                       \
  asm volatile("s_waitcnt vmcnt(" #N ")\n\ts_barrier" ::: "memory");            \
  __builtin_amdgcn_sched_barrier(0);                                            \
} while(0)

__global__ __launch_bounds__(256, 2) void k_step(
    const char* __restrict__ cpad_s, const char* __restrict__ hpad_s,
    char* __restrict__ cpad_d, char* __restrict__ hpad_d,
    const char* __restrict__ w2, const float* __restrict__ y,
    float* __restrict__ cstate, float* __restrict__ out, int t)
{
  extern __shared__ __align__(16) char smem[];
  const int tid = threadIdx.x;
  const int w = tid >> 6, lane = tid & 63;
  const int l15 = lane & 15, l4 = lane >> 4;
  const int og2 = w >> 1, ch = w & 1;
  const int bid = blockIdx.x;
  const int oh = bid & 1, row = (bid >> 1) & 63, n = bid >> 7;
  const int tp = bid % 9;

  /* acc init from y (conv1 + bias precomputed) */
  const float* yb = y + ((size_t)(t*4+n)*4096 + (size_t)row*64)*192;
  const int ocb = ((oh<<1) + og2)*16;
  f32x4 acc[3][2];
  #pragma unroll
  for (int cf = 0; cf < 2; ++cf){
    const int col = (ch<<5) + (cf<<4) + l15;
    #pragma unroll
    for (int gate = 0; gate < 3; ++gate)
      acc[gate][cf] = *(const f32x4*)(yb + (size_t)col*192 + gate*64 + ocb + l4*4);
  }

  /* cstate prefetch */
  const size_t cb = ((size_t)(n*64)) << 12;
  const int gc0 = ocb + l4*4;
  float cpv[8];
  #pragma unroll
  for (int cf = 0; cf < 2; ++cf){
    const int p = (row<<6) + (ch<<5) + (cf<<4) + l15;
    #pragma unroll
    for (int reg = 0; reg < 4; ++reg)
      cpv[cf*4+reg] = cstate[cb + (((size_t)(gc0+reg))<<12) + p];
  }

  STAGE2(0); STAGE2(1); STAGE2(2);

  const char* gsrc[2] = { cpad_s + (size_t)n*IMG_BYTES + (size_t)row*8448,
                          hpad_s + (size_t)n*IMG_BYTES + (size_t)row*8448 };
  #pragma unroll
  for (int jj = 0; jj < 2; ++jj){
    const char* gbj = gsrc[jj];
    for (int i = tid; i < 1584; i += 256){
      int rr = i / 528, iw = i % 528;
      *(uint4*)(smem + rr*9504 + (iw>>3)*144 + (iw&7)*16) =
          *(const uint4*)(gbj + rr*8448 + iw*16);
    }
    __syncthreads();   /* drains vmcnt + lgkmcnt */

    #pragma unroll
    for (int tt = 0; tt < 9; ++tt){
      const int u = jj*9 + tt;
      if (u <= 14) STAGE2(u+3);
      {
        int tv = tt + tp; if (tv >= 9) tv -= 9;
        const int kh = tv/3, kw = tv - kh*3;
        const char* ab0 = smem + 28512 + (u&3)*12288 + og2*1024 + lane*16;
        const char* ib0 = smem + kh*9504 + ((ch<<5) + kw + l15)*144 + (l4<<4);
        #pragma unroll
        for (int cc = 0; cc < 2; ++cc){
          short8 af = *(const short8*)(ab0 + cc*6144);
          short8 ao = *(const short8*)(ab0 + cc*6144 + 2048);
          short8 ag = *(const short8*)(ab0 + cc*6144 + 4096);
          #pragma unroll
          for (int cf = 0; cf < 2; ++cf){
            short8 bf = *(const short8*)(ib0 + (cf<<4)*144 + (cc<<6));
            acc[0][cf] = __builtin_amdgcn_mfma_f32_16x16x32_bf16(af, bf, acc[0][cf], 0,0,0);
            acc[1][cf] = __builtin_amdgcn_mfma_f32_16x16x32_bf16(ao, bf, acc[1][cf], 0,0,0);
            acc[2][cf] = __builtin_amdgcn_mfma_f32_16x16x32_bf16(ag, bf, acc[2][cf], 0,0,0);
          }
        }
      }
      if (u <= 14)      WAITN_BAR(6);
      else if (u == 15) WAITN_BAR(3);
      else if (u == 16) WAITN_BAR(0);
    }
  }

  __syncthreads();   /* input LDS area now reusable for h/c transpose */

  /* gates; out/cstate stores; h/c bf16 into LDS for coalesced pad writes */
  const size_t ob = ((size_t)((t*4+n)*64)) << 12;
  #pragma unroll
  for (int cf = 0; cf < 2; ++cf){
    const int col = (ch<<5) + (cf<<4) + l15;
    const int p = (row<<6) + col;
    union { u16 u[4]; uint2 v; } hp, cp2;
    #pragma unroll
    for (int reg = 0; reg < 4; ++reg){
      const int gc = gc0 + reg;
      float f  = sigm(acc[0][cf][reg]);
      float og_ = sigm(acc[1][cf][reg]);
      float g  = tanh_(acc[2][cf][reg]);
      float cn = f*cpv[cf*4+reg] + (1.f-f)*g;
      float hn = og_ * tanh_(cn);
      cstate[cb + (((size_t)gc)<<12) + p] = cn;
      out[ob + (((size_t)gc)<<12) + p] = hn;
      hp.u[reg]  = f2b(hn);
      cp2.u[reg] = f2b(cn);
    }
    *(uint2*)(smem + col*64 + og2*32 + l4*8) = hp.v;
    *(uint2*)(smem + 4096 + col*64 + og2*32 + l4*8) = cp2.v;
  }
  __syncthreads();

  /* coalesced 16B pad stores: block owns och window [oh*32, oh*32+32) */
  {
    const int col = tid >> 2, off = (tid & 3) << 4;
    char* hdst = hpad_d + (size_t)n*IMG_BYTES + (size_t)(row+1)*8448 + (size_t)(col+1)*128 + oh*64 + off;
    char* cdst = cpad_d + (size_t)n*IMG_BYTES + (size_t)(row+1)*8448 + (size_t)(col+1)*128 + oh*64 + off;
    *(uint4*)hdst = *(const uint4*)(smem + col*64 + off);
    *(uint4*)cdst = *(const uint4*)(smem + 4096 + col*64 + off);
  }
}

extern "C" void kernel_launch(void* const* d_in, const int* in_sizes, int n_in,
                              void* d_out, int out_size, void* d_ws, size_t ws_size,
                              hipStream_t stream)
{
  (void)in_sizes; (void)n_in; (void)out_size; (void)ws_size;
  const float* x     = (const float*)d_in[0];
  const float* gamma = (const float*)d_in[1];
  const float* beta  = (const float*)d_in[2];
  const float* c1w   = (const float*)d_in[3];
  const float* c1b   = (const float*)d_in[4];
  const float* wh2h  = (const float*)d_in[5];
  const float* wc2h  = (const float*)d_in[6];
  char* ws  = (char*)d_ws;
  float* out = (float*)d_out;

  hipFuncSetAttribute(reinterpret_cast<const void*>(k_step),
                      hipFuncAttributeMaxDynamicSharedMemorySize, STEP_SMEM);

  char* hpad0 = ws + WS_HC;
  char* cpad0 = ws + WS_HC + (size_t)4*IMG_BYTES;
  char* hpad1 = ws + WS_HC + (size_t)8*IMG_BYTES;
  char* cpad1 = ws + WS_HC + (size_t)12*IMG_BYTES;
  float* y = (float*)(ws + WS_Y);

  hipMemsetAsync(ws + WS_HC, 0, (size_t)16*IMG_BYTES, stream);
  hipMemsetAsync(ws + WS_CSTATE, 0, (size_t)4*64*4096*4, stream);

  k_wt<<<1296, 256, 0, stream>>>(c1w, wc2h, wh2h,
                                 (u16*)(ws + WS_W1), (u16*)(ws + WS_W2));
  k_bnsum<<<1024, 256, 0, stream>>>(x, (float*)(ws + WS_PART));
  k_bnfin<<<1, 64, 0, stream>>>((const float*)(ws + WS_PART), gamma, beta,
                                (float*)(ws + WS_SCALE), (float*)(ws + WS_SHIFT));
  k_bnx<<<4224, 256, 0, stream>>>(x, (const float*)(ws + WS_SCALE),
                                  (const float*)(ws + WS_SHIFT), ws + WS_BNXP);
  k_conv1<<<2048, 512, 0, stream>>>(ws + WS_BNXP, ws + WS_W1, c1b, y);

  for (int t = 0; t < 16; ++t){
    const char* cs = (t & 1) ? cpad1 : cpad0;
    const char* hs = (t & 1) ? hpad1 : hpad0;
    char* cd = (t & 1) ? cpad0 : cpad1;
    char* hd = (t & 1) ? hpad0 : hpad1;
    k_step<<<512, 256, STEP_SMEM, stream>>>(cs, hs, cd, hd,
                                            ws + WS_W2, y,
                                            (float*)(ws + WS_CSTATE), out, t);
  }
}